// Round 10
// baseline (184.324 us; speedup 1.0000x reference)
//
#include <hip/hip_runtime.h>
#include <hip/hip_bf16.h>

#define S_LEN 2048
#define D_MODEL 2048
#define N_HEADS 32
#define N_KV 8
#define HEAD_DIM 64
#define KV_DIM (N_KV * HEAD_DIM)    // 512
#define QKV_N (D_MODEL + 2 * KV_DIM) // 3072

typedef __bf16 bf16_t;
typedef __attribute__((ext_vector_type(8))) __bf16 bf16x8;
typedef __attribute__((ext_vector_type(4))) float f32x4;
typedef __attribute__((ext_vector_type(16))) float f32x16;
typedef __attribute__((ext_vector_type(4))) unsigned int uint4v;
typedef __attribute__((ext_vector_type(2))) unsigned int uint2v;

// ---------------------------------------------------------------------------
// async global->LDS 16B copy. LDS dest must be wave-uniform base + lane*16.
// ---------------------------------------------------------------------------
__device__ __forceinline__ void gload_lds16(const void* g, void* l) {
    __builtin_amdgcn_global_load_lds(
        (const __attribute__((address_space(1))) unsigned char*)g,
        (__attribute__((address_space(3))) unsigned char*)l,
        16, 0, 0);
}

// ---------------------------------------------------------------------------
// Transpose + convert: src [R][C] f32 -> dst [C][R] bf16
// ---------------------------------------------------------------------------
__global__ __launch_bounds__(256) void transpose_convert(const float* __restrict__ src,
                                                         __hip_bfloat16* __restrict__ dst,
                                                         int R, int C) {
    __shared__ float tile[32][33];
    const int bx = blockIdx.x * 32;
    const int by = blockIdx.y * 32;
    const int tx = threadIdx.x;  // 0..31
    const int ty = threadIdx.y;  // 0..7
#pragma unroll
    for (int i = 0; i < 32; i += 8)
        tile[ty + i][tx] = src[(size_t)(by + ty + i) * C + bx + tx];
    __syncthreads();
#pragma unroll
    for (int i = 0; i < 32; i += 8)
        dst[(size_t)(bx + ty + i) * R + by + tx] = __float2bfloat16(tile[tx][ty + i]);
}

// ---------------------------------------------------------------------------
// f32 -> bf16 convert (8 elems/thread)
// ---------------------------------------------------------------------------
__global__ __launch_bounds__(256) void convert_bf16(const float* __restrict__ src,
                                                    __hip_bfloat16* __restrict__ dst) {
    const int i = (blockIdx.x * 256 + threadIdx.x) * 8;
    const float4 a = *reinterpret_cast<const float4*>(src + i);
    const float4 b = *reinterpret_cast<const float4*>(src + i + 4);
    bf16x8 r;
    r[0] = (__bf16)a.x; r[1] = (__bf16)a.y; r[2] = (__bf16)a.z; r[3] = (__bf16)a.w;
    r[4] = (__bf16)b.x; r[5] = (__bf16)b.y; r[6] = (__bf16)b.z; r[7] = (__bf16)b.w;
    *reinterpret_cast<bf16x8*>(dst + i) = r;
}

// ---------------------------------------------------------------------------
// Fused RoPE for Q (32 heads, scaled) and K (8 heads), in-place on QKV.
// ---------------------------------------------------------------------------
__global__ __launch_bounds__(256) void rope_qk(__hip_bfloat16* __restrict__ t,
                                               const float* __restrict__ cos_t,
                                               const float* __restrict__ sin_t) {
    const int idx = blockIdx.x * blockDim.x + threadIdx.x;  // S * 40 * 32
    const int i = idx & 31;
    const int hh = (idx >> 5) % (N_HEADS + N_KV);
    const int s = idx / (32 * (N_HEADS + N_KV));
    const float c = cos_t[s * 32 + i];
    const float sn = sin_t[s * 32 + i];
    int col; float scale;
    if (hh < N_HEADS) { col = hh * HEAD_DIM + 2 * i; scale = 0.125f * 1.44269504f; }
    else { col = D_MODEL + (hh - N_HEADS) * HEAD_DIM + 2 * i; scale = 1.0f; }
    __hip_bfloat16* p = &t[(size_t)s * QKV_N + col];
    const float re = __bfloat162float(p[0]);
    const float im = __bfloat162float(p[1]);
    p[0] = __float2bfloat16((re * c - im * sn) * scale);
    p[1] = __float2bfloat16((re * sn + im * c) * scale);
}

// ---------------------------------------------------------------------------
// V transpose: QKV[s][2560 + hkv*64 + d] -> Vt[(hkv*64+d)][s]
// ---------------------------------------------------------------------------
__global__ __launch_bounds__(256) void transpose_v(const __hip_bfloat16* __restrict__ QKV,
                                                   __hip_bfloat16* __restrict__ Vt) {
    __shared__ __align__(16) __bf16 tile[64][72];
    const int s0 = blockIdx.x * 64;
    const int hkv = blockIdx.y;
    const int tid = threadIdx.x;
    {
        const int r = tid >> 2;
        const int c0 = (tid & 3) * 16;
        const __hip_bfloat16* src = QKV + (size_t)(s0 + r) * QKV_N + D_MODEL + KV_DIM + hkv * HEAD_DIM + c0;
        *reinterpret_cast<bf16x8*>(&tile[r][c0]) = *reinterpret_cast<const bf16x8*>(src);
        *reinterpret_cast<bf16x8*>(&tile[r][c0 + 8]) = *reinterpret_cast<const bf16x8*>(src + 8);
    }
    __syncthreads();
    {
        const int d = tid >> 2;
        const int sc = (tid & 3) * 16;
        bf16x8 o0, o1;
#pragma unroll
        for (int j = 0; j < 8; ++j) { o0[j] = tile[sc + j][d]; o1[j] = tile[sc + 8 + j][d]; }
        __hip_bfloat16* dst = Vt + (size_t)(hkv * HEAD_DIM + d) * S_LEN + s0 + sc;
        *reinterpret_cast<bf16x8*>(dst) = o0;
        *reinterpret_cast<bf16x8*>(dst + 8) = o1;
    }
}

// ---------------------------------------------------------------------------
// GEMM v4: 128x128 tile, BK=32, 4 waves, T4 counted-vmcnt 3-deep pipeline.
// 3 LDS buffers (48 KB -> 3 blocks/CU). Iter kt: issue stage(kt+2), compute
// buf kt, then s_waitcnt vmcnt(4) (drains ONLY stage(kt+1); stage(kt+2)'s
// 4 loads stay in flight across the barrier) + one s_barrier. Tail uses
// vmcnt(0) when no new stage was issued. (row&3) XOR chunk swizzle.
// ---------------------------------------------------------------------------
__device__ inline void storeC(__hip_bfloat16* p, float v) { *p = __float2bfloat16(v); }
__device__ inline void storeC(float* p, float v) { *p = v; }

template <typename OutT>
__global__ __launch_bounds__(256) void gemm_bt(const __hip_bfloat16* __restrict__ A,
                                               const __hip_bfloat16* __restrict__ Bt,
                                               OutT* __restrict__ C,
                                               int M, int N, int K) {
    __shared__ __align__(16) __bf16 As[3][128 * 32];
    __shared__ __align__(16) __bf16 Bs[3][128 * 32];
    const int tid = threadIdx.x;
    const int w = tid >> 6, l = tid & 63;
    const int wr = w >> 1, wc = w & 1;
    const int l4 = l >> 4, l15 = l & 15;
    const int bm = blockIdx.y * 128, bn = blockIdx.x * 128;

    f32x4 acc[4][4];
#pragma unroll
    for (int i = 0; i < 4; ++i)
#pragma unroll
        for (int j = 0; j < 4; ++j) acc[i][j] = (f32x4){0.f, 0.f, 0.f, 0.f};

    const int r0 = tid >> 2;
    const int cc0 = tid & 3;

    // 4 global_load_lds per thread per stage (2 A + 2 B)
    auto stage = [&](int buf, int k0) {
#pragma unroll
        for (int p = 0; p < 2; ++p) {
            const int row = p * 64 + r0;
            const int cs = cc0 ^ (row & 3);
            gload_lds16(&A[(size_t)(bm + row) * K + k0 + cs * 8], &As[buf][(p * 256 + tid) * 8]);
            gload_lds16(&Bt[(size_t)(bn + row) * K + k0 + cs * 8], &Bs[buf][(p * 256 + tid) * 8]);
        }
    };

    const int nk = K >> 5;
    stage(0, 0);
    stage(1, 32);
    asm volatile("s_waitcnt vmcnt(4)" ::: "memory");   // buf0 ready; buf1 in flight
    __builtin_amdgcn_s_barrier();

    int cur = 0;
#pragma unroll 1
    for (int kt = 0; kt < nk; ++kt) {
        if (kt + 2 < nk) stage(cur == 0 ? 2 : cur - 1, (kt + 2) * 32);
        bf16x8 a[4], b[4];
#pragma unroll
        for (int mi = 0; mi < 4; ++mi) {
            const int rr = wr * 64 + mi * 16 + l15;
            a[mi] = *reinterpret_cast<const bf16x8*>(&As[cur][rr * 32 + ((l4 ^ (rr & 3))) * 8]);
        }
#pragma unroll
        for (int ni = 0; ni < 4; ++ni) {
            const int rr = wc * 64 + ni * 16 + l15;
            b[ni] = *reinterpret_cast<const bf16x8*>(&Bs[cur][rr * 32 + ((l4 ^ (rr & 3))) * 8]);
        }
#pragma unroll
        for (int mi = 0; mi < 4; ++mi)
#pragma unroll
            for (int ni = 0; ni < 4; ++ni)
                acc[mi][ni] = __builtin_amdgcn_mfma_f32_16x16x32_bf16(a[mi], b[ni], acc[mi][ni], 0, 0, 0);
        if (kt + 1 < nk) {
            if (kt + 2 < nk) asm volatile("s_waitcnt vmcnt(4)" ::: "memory");
            else             asm volatile("s_waitcnt vmcnt(0)" ::: "memory");
            __builtin_amdgcn_s_barrier();
        }
        cur = (cur == 2) ? 0 : cur + 1;
    }
#pragma unroll
    for (int mi = 0; mi < 4; ++mi)
#pragma unroll
        for (int ni = 0; ni < 4; ++ni)
#pragma unroll
            for (int r = 0; r < 4; ++r) {
                const int row = bm + wr * 64 + mi * 16 + l4 * 4 + r;
                const int col = bn + wc * 64 + ni * 16 + l15;
                storeC(&C[(size_t)row * N + col], acc[mi][ni][r]);
            }
}

// ---------------------------------------------------------------------------
// Flash attention v9 = v7 (KVBLK=64, the 57.6 us structure) + bf16 partials
// + setprio around MFMA clusters. 8 waves x 32 q-rows = 256 q/block,
// swapped-QK in-register softmax, 32x32x16 MFMA, split-KV slices of 8 tiles.
// Q pre-scaled by 1/8*log2e; exp2 domain; defer-max THR=8.
// ---------------------------------------------------------------------------
__device__ __forceinline__ unsigned cvtpk_bf16(float lo, float hi) {
    unsigned w;
    asm("v_cvt_pk_bf16_f32 %0, %1, %2" : "=v"(w) : "v"(lo), "v"(hi));
    return w;
}
template <int R0>
__device__ __forceinline__ bf16x8 build_pfrag(const f32x16& s, int hi) {
    const unsigned A0 = cvtpk_bf16(s[R0 + 0], s[R0 + 1]);
    const unsigned A1 = cvtpk_bf16(s[R0 + 2], s[R0 + 3]);
    const unsigned B0 = cvtpk_bf16(s[R0 + 4], s[R0 + 5]);
    const unsigned B1 = cvtpk_bf16(s[R0 + 6], s[R0 + 7]);
    const unsigned pA0 = __shfl_xor(A0, 32, 64);
    const unsigned pA1 = __shfl_xor(A1, 32, 64);
    const unsigned pB0 = __shfl_xor(B0, 32, 64);
    const unsigned pB1 = __shfl_xor(B1, 32, 64);
    uint4v u;
    u[0] = hi ? pB0 : A0;
    u[1] = hi ? pB1 : A1;
    u[2] = hi ? B0 : pA0;
    u[3] = hi ? B1 : pA1;
    return __builtin_bit_cast(bf16x8, u);
}

__global__ __launch_bounds__(512) void attn_kernel(const __hip_bfloat16* __restrict__ QKV,
                                                   const __hip_bfloat16* __restrict__ Vt,
                                                   __hip_bfloat16* __restrict__ O,
                                                   __hip_bfloat16* __restrict__ Opart,
                                                   float* __restrict__ ms,
                                                   int split) {
    const int h = blockIdx.y;
    const int hkv = h >> 2;
    // map blockIdx.x -> (qc, sl); slices of 8 tiles; ns(qc)=ceil((qc+1)/2)
    int qc = 0, sl = 0, gbase = 0, ns = 1;
    if (!split) {
        qc = 7 - (int)blockIdx.x;
    } else {
        const int x = (int)blockIdx.x;
        int cum = 0;
#pragma unroll
        for (int q = 0; q < 8; ++q) {
            const int n = (q + 2) >> 1;
            if (x >= cum && x < cum + n) { qc = q; sl = x - cum; gbase = cum; }
            cum += n;
        }
        ns = (qc + 2) >> 1;
    }
    const int ntf = 4 * (qc + 1);
    const int t0 = split ? sl * 8 : 0;
    const int t1 = split ? min(t0 + 8, ntf) : ntf;

    const int tid = threadIdx.x;
    const int w = tid >> 6, l = tid & 63;
    const int lq = l & 31, hi = l >> 5;
    const int q0w = qc * 256 + w * 32;
    const int qlane = q0w + lq;

    __shared__ __align__(16) __bf16 Ks[2][64 * 64];  // [kv][d] swizzled
    __shared__ __align__(16) __bf16 Vs[2][64 * 64];  // [d][kv] swizzled

    const __hip_bfloat16* Kg = QKV + D_MODEL + hkv * HEAD_DIM;       // [s][QKV_N]
    const __hip_bfloat16* Vg = Vt + (size_t)hkv * HEAD_DIM * S_LEN;  // [d][S]

    // 512 threads: 1 chunk each per buffer
    auto stage = [&](int buf, int kv0) {
        const int chunk = tid;                    // 0..511
        const int r = chunk >> 3;                 // row 0..63
        const int cs = (chunk & 7) ^ (r & 7);     // pre-swizzled source chunk
        gload_lds16(&Kg[(size_t)(kv0 + r) * QKV_N + cs * 8], &Ks[buf][chunk * 8]);
        gload_lds16(&Vg[(size_t)r * S_LEN + kv0 + cs * 8], &Vs[buf][chunk * 8]);
    };

    // Q as B-operand: lane holds Q[qlane][16f + 8*hi + e]
    bf16x8 qf[4];
#pragma unroll
    for (int f = 0; f < 4; ++f)
        qf[f] = *reinterpret_cast<const bf16x8*>(
            &QKV[(size_t)qlane * QKV_N + h * HEAD_DIM + 16 * f + 8 * hi]);

    f32x16 o0, o1;
#pragma unroll
    for (int r = 0; r < 16; ++r) { o0[r] = 0.f; o1[r] = 0.f; }
    float m_run = -__builtin_inff(), s_run = 0.f;

    stage(0, t0 * 64);

#pragma unroll 1
    for (int t = t0; t < t1; ++t) {
        __syncthreads();                       // tile t staged (vmcnt drained)
        if (t + 1 < t1) stage((t + 1 - t0) & 1, (t + 1) * 64);
        const int kv0 = t * 64;
        if (kv0 <= q0w + 31) {                 // wave-uniform: skip fully-masked
            const __bf16* Kb = Ks[(t - t0) & 1];
            const __bf16* Vb = Vs[(t - t0) & 1];

            // S^T = K · Q^T  (two 32-kv sub-tiles)
            f32x16 s0, s1;
#pragma unroll
            for (int r = 0; r < 16; ++r) { s0[r] = 0.f; s1[r] = 0.f; }
            __builtin_amdgcn_s_setprio(1);
#pragma unroll
            for (int f = 0; f < 4; ++f) {
                const int rr0 = lq;
                const int rr1 = 32 + lq;
                const bf16x8 ka0 = *reinterpret_cast<const bf16x8*>(
                    &Kb[rr0 * 64 + (((2 * f + hi) ^ (rr0 & 7))) * 8]);
                const bf16x8 ka1 = *reinterpret_cast<const bf16x8*>(
                    &Kb[rr1 * 64 + (((2 * f + hi) ^ (rr1 & 7))) * 8]);
                s0 = __builtin_amdgcn_mfma_f32_32x32x16_bf16(ka0, qf[f], s0, 0, 0, 0);
                s1 = __builtin_amdgcn_mfma_f32_32x32x16_bf16(ka1, qf[f], s1, 0, 0, 0);
            }
            __builtin_amdgcn_s_setprio(0);
            // causal mask (only tiles crossing the diagonal)
            if (kv0 + 63 > q0w) {
#pragma unroll
                for (int r = 0; r < 16; ++r) {
                    const int kvb = (r & 3) + 8 * (r >> 2) + 4 * hi;
                    if (kv0 + kvb > qlane) s0[r] = -__builtin_inff();
                    if (kv0 + 32 + kvb > qlane) s1[r] = -__builtin_inff();
                }
            }
            // row max: tree over own 32 regs, then partner exchange
            float ta = fmaxf(s0[0], s1[0]), tb = fmaxf(s0[1], s1[1]);
            float tc = fmaxf(s0[2], s1[2]), td = fmaxf(s0[3], s1[3]);
#pragma unroll
            for (int r = 4; r < 16; r += 4) {
                ta = fmaxf(ta, fmaxf(s0[r], s1[r]));
                tb = fmaxf(tb, fmaxf(s0[r + 1], s1[r + 1]));
                tc = fmaxf(tc, fmaxf(s0[r + 2], s1[r + 2]));
                td = fmaxf(td, fmaxf(s0[r + 3], s1[r + 3]));
            }
            float m_row = fmaxf(fmaxf(ta, tb), fmaxf(tc, td));
            m_row = fmaxf(m_row, __shfl_xor(m_row, 32, 64));

            // defer-max: skip rescale when max grew by <= 8 (exp2 domain)
            if (!__all(m_row <= m_run + 8.0f)) {
                const float mnew = fmaxf(m_run, m_row);
                const float corr = exp2f(m_run - mnew);
                m_run = mnew;
                s_run *= corr;
#pragma unroll
                for (int r = 0; r < 16; ++r) { o0[r] *= corr; o1[r] *= corr; }
            }
            // P = exp2(S - m_run)
#pragma unroll
            for (int r = 0; r < 16; ++r) {
                s0[r] = exp2f(s0[r] - m_run);
                s1[r] = exp2f(s1[r] - m_run);
            }
            // row sum
            float ua = s0[0] + s1[0], ub = s0[1] + s1[1];
            float uc = s0[2] + s1[2], ud = s0[3] + s1[3];
#pragma unroll
            for (int r = 4; r < 16; r += 4) {
                ua += s0[r] + s1[r];
                ub += s0[r + 1] + s1[r + 1];
                uc += s0[r + 2] + s1[r + 2];
                ud += s0[r + 3] + s1[r + 3];
            }
            float rs = (ua + ub) + (uc + ud);
            rs += __shfl_xor(rs, 32, 64);
            s_run += rs;

            // P fragments (k-steps of 16 kv)
            bf16x8 pa[4];
            pa[0] = build_pfrag<0>(s0, hi);
            pa[1] = build_pfrag<8>(s0, hi);
            pa[2] = build_pfrag<0>(s1, hi);
            pa[3] = build_pfrag<8>(s1, hi);

            // O^T += V^T · P^T
            __builtin_amdgcn_s_setprio(1);
#pragma unroll
            for (int ks = 0; ks < 4; ++ks) {
                const int rv0 = lq;
                const int rv1 = 32 + lq;
                const bf16x8 va0 = *reinterpret_cast<const bf16x8*>(
                    &Vb[rv0 * 64 + (((2 * ks + hi) ^ (rv0 & 7))) * 8]);
                const bf16x8 va1 = *reinterpret_cast<const bf16x8*>(
                    &Vb[rv1 * 64 + (((2 * ks + hi) ^ (rv1 & 7))) * 8]);
                o0 = __builtin_amdgcn_mfma_f32_32x32x16_bf16(va0, pa[ks], o0, 0, 0, 0);
                o1 = __builtin_amdgcn_mfma_f32_32x32x16_bf16(va1, pa[ks], o1, 0, 0, 0);
            }
            __builtin_amdgcn_s_setprio(0);
        }
    }

    if (ns == 1) {
        // direct normalized write: O^T[dv][q] -> O[q][h*64+dv]
        const float inv = 1.0f / s_run;
        __hip_bfloat16* orow = O + (size_t)qlane * D_MODEL + h * HEAD_DIM;
#pragma unroll
        for (int rr = 0; rr < 4; ++rr) {
            {
                uint2v u;
                u[0] = cvtpk_bf16(o0[4 * rr] * inv, o0[4 * rr + 1] * inv);
                u[1] = cvtpk_bf16(o0[4 * rr + 2] * inv, o0[4 * rr + 3] * inv);
                *reinterpret_cast<uint2v*>(orow + 8 * rr + 4 * hi) = u;
            }
            {
                uint2v u;
                u[0] = cvtpk_bf16(o1[4 * rr] * inv, o1[4 * rr + 1] * inv);
                u[1] = cvtpk_bf16(o1[4 * rr + 2] * inv, o1[4 * rr + 3] * inv);
                *reinterpret_cast<uint2v*>(orow + 32 + 8 * rr + 4 * hi) = u;
            }
        }
    } else {
        // partial write: unnormalized bf16 O + (m, s) per row
        const int g = h * 20 + gbase + sl;
        const int row = w * 32 + lq;                      // 0..255 within chunk
        __hip_bfloat16* pb = Opart + ((size_t)g * 256 + row) * 64;
#pragma unroll
        for (int rr = 0; rr < 4; ++rr) {
            {
                uint2v u;
                u[0] = cvtpk_bf16(o0[4 * rr], o0[4 * rr + 1]);
                u[1] = cvtpk_bf16(o0[4 * rr + 2], o0[4 * rr + 3]);
                *reinterpret_cast<uint2v*>(pb + 8 * rr + 4 * hi) = u;
            }
            {
                uint2v u;
                u[0] = cvtpk_bf16(o1[4 * rr], o1[4 * rr + 1]);
                u[1] = cvtpk_bf16(o1[4 * rr + 2], o1[4 * rr + 3]);
                *reinterpret_cast<uint2v*>(pb + 32 + 8 * rr + 4 * hi) = u;
            }
        }
        if (hi == 0) {
            const size_t mi = (size_t)g * 256 + row;
            ms[mi * 2] = m_run;
            ms[mi * 2 + 1] = s_run;
        }
    }
}

// ---------------------------------------------------------------------------
// Merge split-KV partials for qc >= 2. grid (6 qc, 8 rowgroup, 32 h), 256 thr.
// ---------------------------------------------------------------------------
__device__ __constant__ int kCum[8] = {0, 1, 2, 4, 6, 9, 12, 16};

__global__ __launch_bounds__(256) void attn_merge(const __hip_bfloat16* __restrict__ Opart,
                                                  const float* __restrict__ ms,
                                                  __hip_bfloat16* __restrict__ O) {
    const int qc = 2 + blockIdx.x;                    // 2..7
    const int h = blockIdx.z;
    const int tid = threadIdx.x;
    const int row = blockIdx.y * 32 + (tid >> 3);     // 0..255
    const int dv0 = (tid & 7) * 8;
    const int ns = (qc + 2) >> 1;                     // 2..4
    const int g0 = h * 20 + kCum[qc];

    float mv[4], sv[4];
    float M = -__builtin_inff();
#pragma unroll
    for (int s = 0; s < 4; ++s) {
        if (s < ns) {
            const size_t mi = (size_t)(g0 + s) * 256 + row;
            mv[s] = ms[mi * 2];
            sv[s] = ms[mi * 2 + 1];
            M = fmaxf(M, mv[s]);
        }
    }
    float S = 0.f;
    float acc[8];
#pragma unroll
    for (int j = 0; j < 8; ++j) acc[j] = 0.f;
#pragma unroll
    for (int s = 0; s < 4; ++s) {
        if (s < ns) {
            const float wgt = exp2f(mv[s] - M);
            S += wgt * sv[s];
            const bf16x8 v = *reinterpret_cast<const bf16x8*>(
                &Opart[((size_t)(g0 + s) * 256 + row) * 64 + dv0]);
#pragma unroll
            for (int j = 0; j < 8; ++j) acc[j] += wgt * (float)v[j];
        }
    }
    const float inv = 1.0f / S;
    uint4v u;
    u[0] = cvtpk_bf16(acc[0] * inv, acc[1] * inv);
    u[1] = cvtpk_bf16(acc[2] * inv, acc[3] * inv);
    u[2] = cvtpk_bf16(acc[4] * inv, acc[5] * inv);
    u[3] = cvtpk_bf16(acc[6] * inv, acc[7] * inv);
    *reinterpret_cast<uint4v*>(&O[(size_t)(qc * 256 + row) * D_MODEL + h * HEAD_DIM + dv0]) = u;
}

// ---------------------------------------------------------------------------
// Launch
// ---------------------------------------------------------------------------
extern "C" void kernel_launch(void* const* d_in, const int* in_sizes, int n_in,
                              void* d_out, int out_size, void* d_ws, size_t ws_size,
                              hipStream_t stream) {
    const float* x  = (const float*)d_in[0];
    const float* wq = (const float*)d_in[1];
    const float* wk = (const float*)d_in[2];
    const float* wv = (const float*)d_in[3];
    const float* wo = (const float*)d_in[4];
    const float* fc = (const float*)d_in[5];
    const float* fs = (const float*)d_in[6];
    float* out = (float*)d_out;

    char* ws = (char*)d_ws;
    __hip_bfloat16* wqkvT = (__hip_bfloat16*)(ws);                 // [3072][2048] bf16, 12 MiB
    __hip_bfloat16* woT   = (__hip_bfloat16*)(ws + (12u << 20));   // [2048][2048], 8 MiB
    __hip_bfloat16* attnb = (__hip_bfloat16*)(ws + (20u << 20));   // [2048][2048], 8 MiB
    __hip_bfloat16* xb    = (__hip_bfloat16*)(ws + (28u << 20));   // [2048][2048], 8 MiB
    __hip_bfloat16* QKV   = (__hip_bfloat16*)(ws + (36u << 20));   // [2048][3072], 12 MiB
    __hip_bfloat16* Vt    = (__hip_bfloat16*)(ws + (48u << 20));   // [512][2048], 2 MiB
    float*          msb   = (float*)(ws + (50u << 20));            // 640*256*2 f32, 1.3 MiB
    __hip_bfloat16* Opart = (__hip_bfloat16*)(ws + (53u << 20));   // 640*256*64 bf16, 21 MiB

    const int split = (ws_size >= (80ull << 20)) ? 1 : 0;

    const dim3 tb(32, 8);
    transpose_convert<<<dim3(D_MODEL / 32, D_MODEL / 32), tb, 0, stream>>>(wq, wqkvT, D_MODEL, D_MODEL);
    transpose_convert<<<dim3(KV_DIM / 32, D_MODEL / 32), tb, 0, stream>>>(wk, wqkvT + (size_t)D_MODEL * D_MODEL, D_MODEL, KV_DIM);
    transpose_convert<<<dim3(KV_DIM / 32, D_MODEL / 32), tb, 0, stream>>>(wv, wqkvT + (size_t)(D_MODEL + KV_DIM) * D_MODEL, D_MODEL, KV_DIM);
    transpose_convert<<<dim3(D_MODEL / 32, D_MODEL / 32), tb, 0, stream>>>(wo, woT, D_MODEL, D_MODEL);
    convert_bf16<<<(S_LEN * D_MODEL) / (256 * 8), 256, 0, stream>>>(x, xb);

    // fused QKV projection: [2048][3072]
    gemm_bt<__hip_bfloat16><<<dim3(QKV_N / 128, S_LEN / 128), 256, 0, stream>>>(xb, wqkvT, QKV, S_LEN, QKV_N, D_MODEL);

    // fused RoPE on Q (scaled by 1/8*log2e) and K
    rope_qk<<<(S_LEN * (N_HEADS + N_KV) * 32) / 256, 256, 0, stream>>>(QKV, fc, fs);

    // V transpose to [hkv*64+d][s]
    transpose_v<<<dim3(S_LEN / 64, N_KV), 256, 0, stream>>>(QKV, Vt);

    // causal GQA flash attention (8 waves, 256 q-rows/block, split-KV)
    if (split) {
        attn_kernel<<<dim3(20, N_HEADS), 512, 0, stream>>>(QKV, Vt, attnb, Opart, msb, 1);
        attn_merge<<<dim3(6, 8, N_HEADS), 256, 0, stream>>>(Opart, msb, attnb);
    } else {
        attn_kernel<<<dim3(8, N_HEADS), 512, 0, stream>>>(QKV, Vt, attnb, Opart, msb, 0);
    }

    // output projection -> f32
    gemm_bt<float><<<dim3(D_MODEL / 128, S_LEN / 128), 256, 0, stream>>>(attnb, woT, out, S_LEN, D_MODEL, D_MODEL);

    (void)in_sizes; (void)n_in; (void)out_size;
}

// Round 11
// 158.444 us; speedup vs baseline: 1.1633x; 1.1633x over previous
//
#include <hip/hip_runtime.h>
#include <hip/hip_bf16.h>

#define S_LEN 2048
#define D_MODEL 2048
#define N_HEADS 32
#define N_KV 8
#define HEAD_DIM 64
#define KV_DIM (N_KV * HEAD_DIM)    // 512
#define QKV_N (D_MODEL + 2 * KV_DIM) // 3072

typedef __bf16 bf16_t;
typedef __attribute__((ext_vector_type(8))) __bf16 bf16x8;
typedef __attribute__((ext_vector_type(4))) float f32x4;
typedef __attribute__((ext_vector_type(16))) float f32x16;
typedef __attribute__((ext_vector_type(4))) unsigned int uint4v;
typedef __attribute__((ext_vector_type(2))) unsigned int uint2v;

// ---------------------------------------------------------------------------
// async global->LDS 16B copy. LDS dest must be wave-uniform base + lane*16.
// ---------------------------------------------------------------------------
__device__ __forceinline__ void gload_lds16(const void* g, void* l) {
    __builtin_amdgcn_global_load_lds(
        (const __attribute__((address_space(1))) unsigned char*)g,
        (__attribute__((address_space(3))) unsigned char*)l,
        16, 0, 0);
}

// ---------------------------------------------------------------------------
// Transpose + convert: src [R][C] f32 -> dst [C][R] bf16
// ---------------------------------------------------------------------------
__global__ __launch_bounds__(256) void transpose_convert(const float* __restrict__ src,
                                                         __hip_bfloat16* __restrict__ dst,
                                                         int R, int C) {
    __shared__ float tile[32][33];
    const int bx = blockIdx.x * 32;
    const int by = blockIdx.y * 32;
    const int tx = threadIdx.x;  // 0..31
    const int ty = threadIdx.y;  // 0..7
#pragma unroll
    for (int i = 0; i < 32; i += 8)
        tile[ty + i][tx] = src[(size_t)(by + ty + i) * C + bx + tx];
    __syncthreads();
#pragma unroll
    for (int i = 0; i < 32; i += 8)
        dst[(size_t)(bx + ty + i) * R + by + tx] = __float2bfloat16(tile[tx][ty + i]);
}

// ---------------------------------------------------------------------------
// f32 -> bf16 convert (8 elems/thread)
// ---------------------------------------------------------------------------
__global__ __launch_bounds__(256) void convert_bf16(const float* __restrict__ src,
                                                    __hip_bfloat16* __restrict__ dst) {
    const int i = (blockIdx.x * 256 + threadIdx.x) * 8;
    const float4 a = *reinterpret_cast<const float4*>(src + i);
    const float4 b = *reinterpret_cast<const float4*>(src + i + 4);
    bf16x8 r;
    r[0] = (__bf16)a.x; r[1] = (__bf16)a.y; r[2] = (__bf16)a.z; r[3] = (__bf16)a.w;
    r[4] = (__bf16)b.x; r[5] = (__bf16)b.y; r[6] = (__bf16)b.z; r[7] = (__bf16)b.w;
    *reinterpret_cast<bf16x8*>(dst + i) = r;
}

// ---------------------------------------------------------------------------
// Fused RoPE for Q (32 heads, scaled) and K (8 heads), in-place on QKV.
// ---------------------------------------------------------------------------
__global__ __launch_bounds__(256) void rope_qk(__hip_bfloat16* __restrict__ t,
                                               const float* __restrict__ cos_t,
                                               const float* __restrict__ sin_t) {
    const int idx = blockIdx.x * blockDim.x + threadIdx.x;  // S * 40 * 32
    const int i = idx & 31;
    const int hh = (idx >> 5) % (N_HEADS + N_KV);
    const int s = idx / (32 * (N_HEADS + N_KV));
    const float c = cos_t[s * 32 + i];
    const float sn = sin_t[s * 32 + i];
    int col; float scale;
    if (hh < N_HEADS) { col = hh * HEAD_DIM + 2 * i; scale = 0.125f * 1.44269504f; }
    else { col = D_MODEL + (hh - N_HEADS) * HEAD_DIM + 2 * i; scale = 1.0f; }
    __hip_bfloat16* p = &t[(size_t)s * QKV_N + col];
    const float re = __bfloat162float(p[0]);
    const float im = __bfloat162float(p[1]);
    p[0] = __float2bfloat16((re * c - im * sn) * scale);
    p[1] = __float2bfloat16((re * sn + im * c) * scale);
}

// ---------------------------------------------------------------------------
// V transpose: QKV[s][2560 + hkv*64 + d] -> Vt[(hkv*64+d)][s]
// ---------------------------------------------------------------------------
__global__ __launch_bounds__(256) void transpose_v(const __hip_bfloat16* __restrict__ QKV,
                                                   __hip_bfloat16* __restrict__ Vt) {
    __shared__ __align__(16) __bf16 tile[64][72];
    const int s0 = blockIdx.x * 64;
    const int hkv = blockIdx.y;
    const int tid = threadIdx.x;
    {
        const int r = tid >> 2;
        const int c0 = (tid & 3) * 16;
        const __hip_bfloat16* src = QKV + (size_t)(s0 + r) * QKV_N + D_MODEL + KV_DIM + hkv * HEAD_DIM + c0;
        *reinterpret_cast<bf16x8*>(&tile[r][c0]) = *reinterpret_cast<const bf16x8*>(src);
        *reinterpret_cast<bf16x8*>(&tile[r][c0 + 8]) = *reinterpret_cast<const bf16x8*>(src + 8);
    }
    __syncthreads();
    {
        const int d = tid >> 2;
        const int sc = (tid & 3) * 16;
        bf16x8 o0, o1;
#pragma unroll
        for (int j = 0; j < 8; ++j) { o0[j] = tile[sc + j][d]; o1[j] = tile[sc + 8 + j][d]; }
        __hip_bfloat16* dst = Vt + (size_t)(hkv * HEAD_DIM + d) * S_LEN + s0 + sc;
        *reinterpret_cast<bf16x8*>(dst) = o0;
        *reinterpret_cast<bf16x8*>(dst + 8) = o1;
    }
}

// ---------------------------------------------------------------------------
// GEMM v5: 128x128 tile, BK=64, 4 waves, 2-phase prefetch (dbuf LDS,
// stage(t+1) before compute(t), one vmcnt(0)+s_barrier per K-step).
// BK=64 halves the barrier/drain count vs BK=32 (m233: drain dominates);
// occupancy unaffected because grids here are <=1.5 blocks/CU (grid-limited,
// not LDS-limited). Full (row&7) XOR chunk swizzle (8 chunks/row).
// unroll 2 keeps `cur` compile-time (R9 lesson: dynamic LDS indexing costs).
// ---------------------------------------------------------------------------
__device__ inline void storeC(__hip_bfloat16* p, float v) { *p = __float2bfloat16(v); }
__device__ inline void storeC(float* p, float v) { *p = v; }

template <typename OutT>
__global__ __launch_bounds__(256) void gemm_bt(const __hip_bfloat16* __restrict__ A,
                                               const __hip_bfloat16* __restrict__ Bt,
                                               OutT* __restrict__ C,
                                               int M, int N, int K) {
    __shared__ __align__(16) __bf16 As[2][128 * 64];   // 16 KB x2
    __shared__ __align__(16) __bf16 Bs[2][128 * 64];   // 16 KB x2
    const int tid = threadIdx.x;
    const int w = tid >> 6, l = tid & 63;
    const int wr = w >> 1, wc = w & 1;
    const int l4 = l >> 4, l15 = l & 15;
    const int bm = blockIdx.y * 128, bn = blockIdx.x * 128;

    f32x4 acc[4][4];
#pragma unroll
    for (int i = 0; i < 4; ++i)
#pragma unroll
        for (int j = 0; j < 4; ++j) acc[i][j] = (f32x4){0.f, 0.f, 0.f, 0.f};

    // stage: 1024 16B-chunks per array (8 chunks/row of 64 cols); 4/thread
    auto stage = [&](int buf, int k0) {
#pragma unroll
        for (int p = 0; p < 4; ++p) {
            const int chunk = p * 256 + tid;
            const int row = chunk >> 3;
            const int cs = (chunk & 7) ^ (row & 7);   // pre-swizzled source chunk
            gload_lds16(&A[(size_t)(bm + row) * K + k0 + cs * 8], &As[buf][chunk * 8]);
            gload_lds16(&Bt[(size_t)(bn + row) * K + k0 + cs * 8], &Bs[buf][chunk * 8]);
        }
    };

    const int nk = K >> 6;   // BK=64 steps
    stage(0, 0);
    asm volatile("s_waitcnt vmcnt(0)" ::: "memory");
    __builtin_amdgcn_s_barrier();

#pragma unroll 2
    for (int kt = 0; kt < nk; ++kt) {
        const int cur = kt & 1;
        if (kt + 1 < nk) stage(cur ^ 1, (kt + 1) * 64);   // prefetch next tile
#pragma unroll
        for (int ks = 0; ks < 2; ++ks) {
            bf16x8 a[4], b[4];
#pragma unroll
            for (int mi = 0; mi < 4; ++mi) {
                const int rr = wr * 64 + mi * 16 + l15;
                a[mi] = *reinterpret_cast<const bf16x8*>(
                    &As[cur][rr * 64 + (((ks * 4 + l4) ^ (rr & 7))) * 8]);
            }
#pragma unroll
            for (int ni = 0; ni < 4; ++ni) {
                const int rr = wc * 64 + ni * 16 + l15;
                b[ni] = *reinterpret_cast<const bf16x8*>(
                    &Bs[cur][rr * 64 + (((ks * 4 + l4) ^ (rr & 7))) * 8]);
            }
#pragma unroll
            for (int mi = 0; mi < 4; ++mi)
#pragma unroll
                for (int ni = 0; ni < 4; ++ni)
                    acc[mi][ni] = __builtin_amdgcn_mfma_f32_16x16x32_bf16(a[mi], b[ni], acc[mi][ni], 0, 0, 0);
        }
        // publish next tile (prefetch latency hidden under 32 MFMAs) + quiesce
        asm volatile("s_waitcnt vmcnt(0)" ::: "memory");
        __builtin_amdgcn_s_barrier();
    }
#pragma unroll
    for (int mi = 0; mi < 4; ++mi)
#pragma unroll
        for (int ni = 0; ni < 4; ++ni)
#pragma unroll
            for (int r = 0; r < 4; ++r) {
                const int row = bm + wr * 64 + mi * 16 + l4 * 4 + r;
                const int col = bn + wc * 64 + ni * 16 + l15;
                storeC(&C[(size_t)row * N + col], acc[mi][ni][r]);
            }
}

// ---------------------------------------------------------------------------
// permlane32_swap: swaps x[hi lanes] with y[lo lanes].
//   new_x[l] = l<32 ? x[l] : y[l-32];  new_y[l] = l<32 ? x[l+32] : y[l]
// VALU-pipe (1.20x vs ds_bpermute, m255). Fallback emulation via shfl.
// ---------------------------------------------------------------------------
#if __has_builtin(__builtin_amdgcn_permlane32_swap)
__device__ __forceinline__ void plswap(unsigned& x, unsigned& y, int) {
    uint2v r = __builtin_amdgcn_permlane32_swap(x, y, false, false);
    x = r[0]; y = r[1];
}
#else
__device__ __forceinline__ void plswap(unsigned& x, unsigned& y, int hi) {
    const unsigned px = __shfl_xor(x, 32, 64);
    const unsigned py = __shfl_xor(y, 32, 64);
    const unsigned nx = hi ? py : x;
    const unsigned ny = hi ? y : px;
    x = nx; y = ny;
}
#endif

__device__ __forceinline__ unsigned cvtpk_bf16(float lo, float hi) {
    unsigned w;
    asm("v_cvt_pk_bf16_f32 %0, %1, %2" : "=v"(w) : "v"(lo), "v"(hi));
    return w;
}
__device__ __forceinline__ float swap_max(float v, int hi) {
    unsigned x = __builtin_bit_cast(unsigned, v), y = x;
    plswap(x, y, hi);
    return fmaxf(__builtin_bit_cast(float, x), __builtin_bit_cast(float, y));
}
__device__ __forceinline__ float swap_add(float v, int hi) {
    unsigned x = __builtin_bit_cast(unsigned, v), y = x;
    plswap(x, y, hi);
    return __builtin_bit_cast(float, x) + __builtin_bit_cast(float, y);
}
// Build PV B-fragment for one 16-kv k-step from 8 own p-values s[R0..R0+7].
// swap(A0,B0) -> (u[0], u[2]); swap(A1,B1) -> (u[1], u[3]).  [T12, m214v22]
template <int R0>
__device__ __forceinline__ bf16x8 build_pfrag(const f32x16& s, int hi) {
    unsigned A0 = cvtpk_bf16(s[R0 + 0], s[R0 + 1]);
    unsigned A1 = cvtpk_bf16(s[R0 + 2], s[R0 + 3]);
    unsigned B0 = cvtpk_bf16(s[R0 + 4], s[R0 + 5]);
    unsigned B1 = cvtpk_bf16(s[R0 + 6], s[R0 + 7]);
    plswap(A0, B0, hi);
    plswap(A1, B1, hi);
    uint4v u; u[0] = A0; u[1] = A1; u[2] = B0; u[3] = B1;
    return __builtin_bit_cast(bf16x8, u);
}

// ---------------------------------------------------------------------------
// Flash attention v10 = v9 structure (KVBLK=64, 8 waves x 32 q-rows,
// swapped-QK in-register softmax, split-KV slices of 8 tiles, bf16
// partials, setprio) with permlane32_swap replacing all shfl exchanges.
// ---------------------------------------------------------------------------
__global__ __launch_bounds__(512) void attn_kernel(const __hip_bfloat16* __restrict__ QKV,
                                                   const __hip_bfloat16* __restrict__ Vt,
                                                   __hip_bfloat16* __restrict__ O,
                                                   __hip_bfloat16* __restrict__ Opart,
                                                   float* __restrict__ ms,
                                                   int split) {
    const int h = blockIdx.y;
    const int hkv = h >> 2;
    // map blockIdx.x -> (qc, sl); slices of 8 tiles; ns(qc)=ceil((qc+1)/2)
    int qc = 0, sl = 0, gbase = 0, ns = 1;
    if (!split) {
        qc = 7 - (int)blockIdx.x;
    } else {
        const int x = (int)blockIdx.x;
        int cum = 0;
#pragma unroll
        for (int q = 0; q < 8; ++q) {
            const int n = (q + 2) >> 1;
            if (x >= cum && x < cum + n) { qc = q; sl = x - cum; gbase = cum; }
            cum += n;
        }
        ns = (qc + 2) >> 1;
    }
    const int ntf = 4 * (qc + 1);
    const int t0 = split ? sl * 8 : 0;
    const int t1 = split ? min(t0 + 8, ntf) : ntf;

    const int tid = threadIdx.x;
    const int w = tid >> 6, l = tid & 63;
    const int lq = l & 31, hi = l >> 5;
    const int q0w = qc * 256 + w * 32;
    const int qlane = q0w + lq;

    __shared__ __align__(16) __bf16 Ks[2][64 * 64];  // [kv][d] swizzled
    __shared__ __align__(16) __bf16 Vs[2][64 * 64];  // [d][kv] swizzled

    const __hip_bfloat16* Kg = QKV + D_MODEL + hkv * HEAD_DIM;       // [s][QKV_N]
    const __hip_bfloat16* Vg = Vt + (size_t)hkv * HEAD_DIM * S_LEN;  // [d][S]

    // 512 threads: 1 chunk each per buffer
    auto stage = [&](int buf, int kv0) {
        const int chunk = tid;                    // 0..511
        const int r = chunk >> 3;                 // row 0..63
        const int cs = (chunk & 7) ^ (r & 7);     // pre-swizzled source chunk
        gload_lds16(&Kg[(size_t)(kv0 + r) * QKV_N + cs * 8], &Ks[buf][chunk * 8]);
        gload_lds16(&Vg[(size_t)r * S_LEN + kv0 + cs * 8], &Vs[buf][chunk * 8]);
    };

    // Q as B-operand: lane holds Q[qlane][16f + 8*hi + e]
    bf16x8 qf[4];
#pragma unroll
    for (int f = 0; f < 4; ++f)
        qf[f] = *reinterpret_cast<const bf16x8*>(
            &QKV[(size_t)qlane * QKV_N + h * HEAD_DIM + 16 * f + 8 * hi]);

    f32x16 o0, o1;
#pragma unroll
    for (int r = 0; r < 16; ++r) { o0[r] = 0.f; o1[r] = 0.f; }
    float m_run = -__builtin_inff(), s_run = 0.f;

    stage(0, t0 * 64);

#pragma unroll 1
    for (int t = t0; t < t1; ++t) {
        __syncthreads();                       // tile t staged (vmcnt drained)
        if (t + 1 < t1) stage((t + 1 - t0) & 1, (t + 1) * 64);
        const int kv0 = t * 64;
        if (kv0 <= q0w + 31) {                 // wave-uniform: skip fully-masked
            const __bf16* Kb = Ks[(t - t0) & 1];
            const __bf16* Vb = Vs[(t - t0) & 1];

            // S^T = K · Q^T  (two 32-kv sub-tiles)
            f32x16 s0, s1;
#pragma unroll
            for (int r = 0; r < 16; ++r) { s0[r] = 0.f; s1[r] = 0.f; }
            __builtin_amdgcn_s_setprio(1);
#pragma unroll
            for (int f = 0; f < 4; ++f) {
                const int rr0 = lq;
                const int rr1 = 32 + lq;
                const bf16x8 ka0 = *reinterpret_cast<const bf16x8*>(
                    &Kb[rr0 * 64 + (((2 * f + hi) ^ (rr0 & 7))) * 8]);
                const bf16x8 ka1 = *reinterpret_cast<const bf16x8*>(
                    &Kb[rr1 * 64 + (((2 * f + hi) ^ (rr1 & 7))) * 8]);
                s0 = __builtin_amdgcn_mfma_f32_32x32x16_bf16(ka0, qf[f], s0, 0, 0, 0);
                s1 = __builtin_amdgcn_mfma_f32_32x32x16_bf16(ka1, qf[f], s1, 0, 0, 0);
            }
            __builtin_amdgcn_s_setprio(0);
            // causal mask (only tiles crossing the diagonal)
            if (kv0 + 63 > q0w) {
#pragma unroll
                for (int r = 0; r < 16; ++r) {
                    const int kvb = (r & 3) + 8 * (r >> 2) + 4 * hi;
                    if (kv0 + kvb > qlane) s0[r] = -__builtin_inff();
                    if (kv0 + 32 + kvb > qlane) s1[r] = -__builtin_inff();
                }
            }
            // row max: tree over own 32 regs, then partner exchange
            float ta = fmaxf(s0[0], s1[0]), tb = fmaxf(s0[1], s1[1]);
            float tc = fmaxf(s0[2], s1[2]), td = fmaxf(s0[3], s1[3]);
#pragma unroll
            for (int r = 4; r < 16; r += 4) {
                ta = fmaxf(ta, fmaxf(s0[r], s1[r]));
                tb = fmaxf(tb, fmaxf(s0[r + 1], s1[r + 1]));
                tc = fmaxf(tc, fmaxf(s0[r + 2], s1[r + 2]));
                td = fmaxf(td, fmaxf(s0[r + 3], s1[r + 3]));
            }
            const float m_row = swap_max(fmaxf(fmaxf(ta, tb), fmaxf(tc, td)), hi);

            // defer-max: skip rescale when max grew by <= 8 (exp2 domain)
            if (!__all(m_row <= m_run + 8.0f)) {
                const float mnew = fmaxf(m_run, m_row);
                const float corr = exp2f(m_run - mnew);
                m_run = mnew;
                s_run *= corr;
#pragma unroll
                for (int r = 0; r < 16; ++r) { o0[r] *= corr; o1[r] *= corr; }
            }
            // P = exp2(S - m_run)
#pragma unroll
            for (int r = 0; r < 16; ++r) {
                s0[r] = exp2f(s0[r] - m_run);
                s1[r] = exp2f(s1[r] - m_run);
            }
            // row sum
            float ua = s0[0] + s1[0], ub = s0[1] + s1[1];
            float uc = s0[2] + s1[2], ud = s0[3] + s1[3];
#pragma unroll
            for (int r = 4; r < 16; r += 4) {
                ua += s0[r] + s1[r];
                ub += s0[r + 1] + s1[r + 1];
                uc += s0[r + 2] + s1[r + 2];
                ud += s0[r + 3] + s1[r + 3];
            }
            s_run += swap_add((ua + ub) + (uc + ud), hi);

            // P fragments (k-steps of 16 kv)
            bf16x8 pa[4];
            pa[0] = build_pfrag<0>(s0, hi);
            pa[1] = build_pfrag<8>(s0, hi);
            pa[2] = build_pfrag<0>(s1, hi);
            pa[3] = build_pfrag<8>(s1, hi);

            // O^T += V^T · P^T
            __builtin_amdgcn_s_setprio(1);
#pragma unroll
            for (int ks = 0; ks < 4; ++ks) {
                const int rv0 = lq;
                const int rv1 = 32 + lq;
                const bf16x8 va0 = *reinterpret_cast<const bf16x8*>(
                    &Vb[rv0 * 64 + (((2 * ks + hi) ^ (rv0 & 7))) * 8]);
                const bf16x8 va1 = *reinterpret_cast<const bf16x8*>(
                    &Vb[rv1 * 64 + (((2 * ks + hi) ^ (rv1 & 7))) * 8]);
                o0 = __builtin_amdgcn_mfma_f32_32x32x16_bf16(va0, pa[ks], o0, 0, 0, 0);
                o1 = __builtin_amdgcn_mfma_f32_32x32x16_bf16(va1, pa[ks], o1, 0, 0, 0);
            }
            __builtin_amdgcn_s_setprio(0);
        }
    }

    if (ns == 1) {
        // direct normalized write: O^T[dv][q] -> O[q][h*64+dv]
        const float inv = 1.0f / s_run;
        __hip_bfloat16* orow = O + (size_t)qlane * D_MODEL + h * HEAD_DIM;
#pragma unroll
        for (int rr = 0; rr < 4; ++rr) {
            {
                uint2v u;
                u[0] = cvtpk_bf16(o0[4 * rr] * inv, o0[4 * rr + 1] * inv);
                u[1] = cvtpk_bf16(o0[4 * rr + 2] * inv, o0[4 * rr + 3] * inv);
                *reinterpret_cast<uint2v*>(orow + 8 * rr + 4 * hi) = u;
            }
            {
                uint2v u;
                u[0] = cvtpk_bf16(o1[4 * rr] * inv, o1[4 * rr + 1] * inv);
                u[1] = cvtpk_bf16(o1[4 * rr + 2] * inv, o1[4 * rr + 3] * inv);
                *reinterpret_cast<uint2v*>(orow + 32 + 8 * rr + 4 * hi) = u;
            }
        }
    } else {
        // partial write: unnormalized bf16 O + (m, s) per row
        const int g = h * 20 + gbase + sl;
        const int row = w * 32 + lq;                      // 0..255 within chunk
        __hip_bfloat16* pb = Opart + ((size_t)g * 256 + row) * 64;
#pragma unroll
        for (int rr = 0; rr < 4; ++rr) {
            {
                uint2v u;
                u[0] = cvtpk_bf16(o0[4 * rr], o0[4 * rr + 1]);
                u[1] = cvtpk_bf16(o0[4 * rr + 2], o0[4 * rr + 3]);
                *reinterpret_cast<uint2v*>(pb + 8 * rr + 4 * hi) = u;
            }
            {
                uint2v u;
                u[0] = cvtpk_bf16(o1[4 * rr], o1[4 * rr + 1]);
                u[1] = cvtpk_bf16(o1[4 * rr + 2], o1[4 * rr + 3]);
                *reinterpret_cast<uint2v*>(pb + 32 + 8 * rr + 4 * hi) = u;
            }
        }
        if (hi == 0) {
            const size_t mi = (size_t)g * 256 + row;
            ms[mi * 2] = m_run;
            ms[mi * 2 + 1] = s_run;
        }
    }
}

// ---------------------------------------------------------------------------
// Merge split-KV partials for qc >= 2. grid (6 qc, 8 rowgroup, 32 h), 256 thr.
// ---------------------------------------------------------------------------
__device__ __constant__ int kCum[8] = {0, 1, 2, 4, 6, 9, 12, 16};

__global__ __launch_bounds__(256) void attn_merge(const __hip_bfloat16* __restrict__ Opart,
                                                  const float* __restrict__ ms,
                                                  __hip_bfloat16* __restrict__ O) {
    const int qc = 2 + blockIdx.x;                    // 2..7
    const int h = blockIdx.z;
    const int tid = threadIdx.x;
    const int row = blockIdx.y * 32 + (tid >> 3);     // 0..255
    const int dv0 = (tid & 7) * 8;
    const int ns = (qc + 2) >> 1;                     // 2..4
    const int g0 = h * 20 + kCum[qc];

    float mv[4], sv[4];
    float M = -__builtin_inff();
#pragma unroll
    for (int s = 0; s < 4; ++s) {
        if (s < ns) {
            const size_t mi = (size_t)(g0 + s) * 256 + row;
            mv[s] = ms[mi * 2];
            sv[s] = ms[mi * 2 + 1];
            M = fmaxf(M, mv[s]);
        }
    }
    float S = 0.f;
    float acc[8];
#pragma unroll
    for (int j = 0; j < 8; ++j) acc[j] = 0.f;
#pragma unroll
    for (int s = 0; s < 4; ++s) {
        if (s < ns) {
            const float wgt = exp2f(mv[s] - M);
            S += wgt * sv[s];
            const bf16x8 v = *reinterpret_cast<const bf16x8*>(
                &Opart[((size_t)(g0 + s) * 256 + row) * 64 + dv0]);
#pragma unroll
            for (int j = 0; j < 8; ++j) acc[j] += wgt * (float)v[j];
        }
    }
    const float inv = 1.0f / S;
    uint4v u;
    u[0] = cvtpk_bf16(acc[0] * inv, acc[1] * inv);
    u[1] = cvtpk_bf16(acc[2] * inv, acc[3] * inv);
    u[2] = cvtpk_bf16(acc[4] * inv, acc[5] * inv);
    u[3] = cvtpk_bf16(acc[6] * inv, acc[7] * inv);
    *reinterpret_cast<uint4v*>(&O[(size_t)(qc * 256 + row) * D_MODEL + h * HEAD_DIM + dv0]) = u;
}

// ---------------------------------------------------------------------------
// Launch
// ---------------------------------------------------------------------------
extern "C" void kernel_launch(void* const* d_in, const int* in_sizes, int n_in,
                              void* d_out, int out_size, void* d_ws, size_t ws_size,
                              hipStream_t stream) {
    const float* x  = (const float*)d_in[0];
    const float* wq = (const float*)d_in[1];
    const float* wk = (const float*)d_in[2];
    const float* wv = (const float*)d_in[3];
    const float* wo = (const float*)d_in[4];
    const float* fc = (const float*)d_in[5];
    const float* fs = (const float*)d_in[6];
    float* out = (float*)d_out;

    char* ws = (char*)d_ws;
    __hip_bfloat16* wqkvT = (__hip_bfloat16*)(ws);                 // [3072][2048] bf16, 12 MiB
    __hip_bfloat16* woT   = (__hip_bfloat16*)(ws + (12u << 20));   // [2048][2048], 8 MiB
    __hip_bfloat16* attnb = (__hip_bfloat16*)(ws + (20u << 20));   // [2048][2048], 8 MiB
    __hip_bfloat16* xb    = (__hip_bfloat16*)(ws + (28u << 20));   // [2048][2048], 8 MiB
    __hip_bfloat16* QKV   = (__hip_bfloat16*)(ws + (36u << 20));   // [2048][3072], 12 MiB
    __hip_bfloat16* Vt    = (__hip_bfloat16*)(ws + (48u << 20));   // [512][2048], 2 MiB
    float*          msb   = (float*)(ws + (50u << 20));            // 640*256*2 f32, 1.3 MiB
    __hip_bfloat16* Opart = (__hip_bfloat16*)(ws + (53u << 20));   // 640*256*64 bf16, 21 MiB

    const int split = (ws_size >= (80ull << 20)) ? 1 : 0;

    const dim3 tb(32, 8);
    transpose_convert<<<dim3(D_MODEL / 32, D_MODEL / 32), tb, 0, stream>>>(wq, wqkvT, D_MODEL, D_MODEL);
    transpose_convert<<<dim3(KV_DIM / 32, D_MODEL / 32), tb, 0, stream>>>(wk, wqkvT + (size_t)D_MODEL * D_MODEL, D_MODEL, KV_DIM);
    transpose_convert<<<dim3(KV_DIM / 32, D_MODEL / 32), tb, 0, stream>>>(wv, wqkvT + (size_t)(D_MODEL + KV_DIM) * D_MODEL, D_MODEL, KV_DIM);
    transpose_convert<<<dim3(D_MODEL / 32, D_MODEL / 32), tb, 0, stream>>>(wo, woT, D_MODEL, D_MODEL);
    convert_bf16<<<(S_LEN * D_MODEL) / (256 * 8), 256, 0, stream>>>(x, xb);

    // fused QKV projection: [2048][3072]
    gemm_bt<__hip_bfloat16><<<dim3(QKV_N / 128, S_LEN / 128), 256, 0, stream>>>(xb, wqkvT, QKV, S_LEN, QKV_N, D_MODEL);

    // fused RoPE on Q (scaled by 1/8*log2e) and K
    rope_qk<<<(S_LEN * (N_HEADS + N_KV) * 32) / 256, 256, 0, stream>>>(QKV, fc, fs);

    // V transpose to [hkv*64+d][s]
    transpose_v<<<dim3(S_LEN / 64, N_KV), 256, 0, stream>>>(QKV, Vt);

    // causal GQA flash attention (8 waves, 256 q-rows/block, split-KV)
    if (split) {
        attn_kernel<<<dim3(20, N_HEADS), 512, 0, stream>>>(QKV, Vt, attnb, Opart, msb, 1);
        attn_merge<<<dim3(6, 8, N_HEADS), 256, 0, stream>>>(Opart, msb, attnb);
    } else {
        attn_kernel<<<dim3(8, N_HEADS), 512, 0, stream>>>(QKV, Vt, attnb, Opart, msb, 0);
    }

    // output projection -> f32
    gemm_bt<float><<<dim3(D_MODEL / 128, S_LEN / 128), 256, 0, stream>>>(attnb, woT, out, S_LEN, D_MODEL, D_MODEL);

    (void)in_sizes; (void)n_in; (void)out_size;
}

// Round 12
// 156.178 us; speedup vs baseline: 1.1802x; 1.0145x over previous
//
#include <hip/hip_runtime.h>
#include <hip/hip_bf16.h>

#define S_LEN 2048
#define D_MODEL 2048
#define N_HEADS 32
#define N_KV 8
#define HEAD_DIM 64
#define KV_DIM (N_KV * HEAD_DIM)    // 512
#define QKV_N (D_MODEL + 2 * KV_DIM) // 3072

typedef __bf16 bf16_t;
typedef __attribute__((ext_vector_type(8))) __bf16 bf16x8;
typedef __attribute__((ext_vector_type(4))) float f32x4;
typedef __attribute__((ext_vector_type(16))) float f32x16;
typedef __attribute__((ext_vector_type(4))) unsigned int uint4v;
typedef __attribute__((ext_vector_type(2))) unsigned int uint2v;

// ---------------------------------------------------------------------------
// async global->LDS 16B copy. LDS dest must be wave-uniform base + lane*16.
// ---------------------------------------------------------------------------
__device__ __forceinline__ void gload_lds16(const void* g, void* l) {
    __builtin_amdgcn_global_load_lds(
        (const __attribute__((address_space(1))) unsigned char*)g,
        (__attribute__((address_space(3))) unsigned char*)l,
        16, 0, 0);
}

// ---------------------------------------------------------------------------
// Transpose + convert: src [R][C] f32 -> dst [C][R] bf16
// ---------------------------------------------------------------------------
__global__ __launch_bounds__(256) void transpose_convert(const float* __restrict__ src,
                                                         __hip_bfloat16* __restrict__ dst,
                                                         int R, int C) {
    __shared__ float tile[32][33];
    const int bx = blockIdx.x * 32;
    const int by = blockIdx.y * 32;
    const int tx = threadIdx.x;  // 0..31
    const int ty = threadIdx.y;  // 0..7
#pragma unroll
    for (int i = 0; i < 32; i += 8)
        tile[ty + i][tx] = src[(size_t)(by + ty + i) * C + bx + tx];
    __syncthreads();
#pragma unroll
    for (int i = 0; i < 32; i += 8)
        dst[(size_t)(bx + ty + i) * R + by + tx] = __float2bfloat16(tile[tx][ty + i]);
}

// ---------------------------------------------------------------------------
// f32 -> bf16 convert (8 elems/thread)
// ---------------------------------------------------------------------------
__global__ __launch_bounds__(256) void convert_bf16(const float* __restrict__ src,
                                                    __hip_bfloat16* __restrict__ dst) {
    const int i = (blockIdx.x * 256 + threadIdx.x) * 8;
    const float4 a = *reinterpret_cast<const float4*>(src + i);
    const float4 b = *reinterpret_cast<const float4*>(src + i + 4);
    bf16x8 r;
    r[0] = (__bf16)a.x; r[1] = (__bf16)a.y; r[2] = (__bf16)a.z; r[3] = (__bf16)a.w;
    r[4] = (__bf16)b.x; r[5] = (__bf16)b.y; r[6] = (__bf16)b.z; r[7] = (__bf16)b.w;
    *reinterpret_cast<bf16x8*>(dst + i) = r;
}

// ---------------------------------------------------------------------------
// Fused RoPE for Q (32 heads, scaled) and K (8 heads), in-place on QKV.
// ---------------------------------------------------------------------------
__global__ __launch_bounds__(256) void rope_qk(__hip_bfloat16* __restrict__ t,
                                               const float* __restrict__ cos_t,
                                               const float* __restrict__ sin_t) {
    const int idx = blockIdx.x * blockDim.x + threadIdx.x;  // S * 40 * 32
    const int i = idx & 31;
    const int hh = (idx >> 5) % (N_HEADS + N_KV);
    const int s = idx / (32 * (N_HEADS + N_KV));
    const float c = cos_t[s * 32 + i];
    const float sn = sin_t[s * 32 + i];
    int col; float scale;
    if (hh < N_HEADS) { col = hh * HEAD_DIM + 2 * i; scale = 0.125f * 1.44269504f; }
    else { col = D_MODEL + (hh - N_HEADS) * HEAD_DIM + 2 * i; scale = 1.0f; }
    __hip_bfloat16* p = &t[(size_t)s * QKV_N + col];
    const float re = __bfloat162float(p[0]);
    const float im = __bfloat162float(p[1]);
    p[0] = __float2bfloat16((re * c - im * sn) * scale);
    p[1] = __float2bfloat16((re * sn + im * c) * scale);
}

// ---------------------------------------------------------------------------
// V transpose: QKV[s][2560 + hkv*64 + d] -> Vt[(hkv*64+d)][s]
// ---------------------------------------------------------------------------
__global__ __launch_bounds__(256) void transpose_v(const __hip_bfloat16* __restrict__ QKV,
                                                   __hip_bfloat16* __restrict__ Vt) {
    __shared__ __align__(16) __bf16 tile[64][72];
    const int s0 = blockIdx.x * 64;
    const int hkv = blockIdx.y;
    const int tid = threadIdx.x;
    {
        const int r = tid >> 2;
        const int c0 = (tid & 3) * 16;
        const __hip_bfloat16* src = QKV + (size_t)(s0 + r) * QKV_N + D_MODEL + KV_DIM + hkv * HEAD_DIM + c0;
        *reinterpret_cast<bf16x8*>(&tile[r][c0]) = *reinterpret_cast<const bf16x8*>(src);
        *reinterpret_cast<bf16x8*>(&tile[r][c0 + 8]) = *reinterpret_cast<const bf16x8*>(src + 8);
    }
    __syncthreads();
    {
        const int d = tid >> 2;
        const int sc = (tid & 3) * 16;
        bf16x8 o0, o1;
#pragma unroll
        for (int j = 0; j < 8; ++j) { o0[j] = tile[sc + j][d]; o1[j] = tile[sc + 8 + j][d]; }
        __hip_bfloat16* dst = Vt + (size_t)(hkv * HEAD_DIM + d) * S_LEN + s0 + sc;
        *reinterpret_cast<bf16x8*>(dst) = o0;
        *reinterpret_cast<bf16x8*>(dst + 8) = o1;
    }
}

// ---------------------------------------------------------------------------
// GEMM v5 (unchanged from R10): 128x128 tile, BK=64, 4 waves, 2-phase
// prefetch (dbuf LDS, stage(t+1) before compute(t), one vmcnt(0)+s_barrier
// per K-step). Full (row&7) XOR chunk swizzle.
// ---------------------------------------------------------------------------
__device__ inline void storeC(__hip_bfloat16* p, float v) { *p = __float2bfloat16(v); }
__device__ inline void storeC(float* p, float v) { *p = v; }

template <typename OutT>
__global__ __launch_bounds__(256) void gemm_bt(const __hip_bfloat16* __restrict__ A,
                                               const __hip_bfloat16* __restrict__ Bt,
                                               OutT* __restrict__ C,
                                               int M, int N, int K) {
    __shared__ __align__(16) __bf16 As[2][128 * 64];   // 16 KB x2
    __shared__ __align__(16) __bf16 Bs[2][128 * 64];   // 16 KB x2
    const int tid = threadIdx.x;
    const int w = tid >> 6, l = tid & 63;
    const int wr = w >> 1, wc = w & 1;
    const int l4 = l >> 4, l15 = l & 15;
    const int bm = blockIdx.y * 128, bn = blockIdx.x * 128;

    f32x4 acc[4][4];
#pragma unroll
    for (int i = 0; i < 4; ++i)
#pragma unroll
        for (int j = 0; j < 4; ++j) acc[i][j] = (f32x4){0.f, 0.f, 0.f, 0.f};

    // stage: 1024 16B-chunks per array (8 chunks/row of 64 cols); 4/thread
    auto stage = [&](int buf, int k0) {
#pragma unroll
        for (int p = 0; p < 4; ++p) {
            const int chunk = p * 256 + tid;
            const int row = chunk >> 3;
            const int cs = (chunk & 7) ^ (row & 7);   // pre-swizzled source chunk
            gload_lds16(&A[(size_t)(bm + row) * K + k0 + cs * 8], &As[buf][chunk * 8]);
            gload_lds16(&Bt[(size_t)(bn + row) * K + k0 + cs * 8], &Bs[buf][chunk * 8]);
        }
    };

    const int nk = K >> 6;   // BK=64 steps
    stage(0, 0);
    asm volatile("s_waitcnt vmcnt(0)" ::: "memory");
    __builtin_amdgcn_s_barrier();

#pragma unroll 2
    for (int kt = 0; kt < nk; ++kt) {
        const int cur = kt & 1;
        if (kt + 1 < nk) stage(cur ^ 1, (kt + 1) * 64);   // prefetch next tile
#pragma unroll
        for (int ks = 0; ks < 2; ++ks) {
            bf16x8 a[4], b[4];
#pragma unroll
            for (int mi = 0; mi < 4; ++mi) {
                const int rr = wr * 64 + mi * 16 + l15;
                a[mi] = *reinterpret_cast<const bf16x8*>(
                    &As[cur][rr * 64 + (((ks * 4 + l4) ^ (rr & 7))) * 8]);
            }
#pragma unroll
            for (int ni = 0; ni < 4; ++ni) {
                const int rr = wc * 64 + ni * 16 + l15;
                b[ni] = *reinterpret_cast<const bf16x8*>(
                    &Bs[cur][rr * 64 + (((ks * 4 + l4) ^ (rr & 7))) * 8]);
            }
#pragma unroll
            for (int mi = 0; mi < 4; ++mi)
#pragma unroll
                for (int ni = 0; ni < 4; ++ni)
                    acc[mi][ni] = __builtin_amdgcn_mfma_f32_16x16x32_bf16(a[mi], b[ni], acc[mi][ni], 0, 0, 0);
        }
        // publish next tile (prefetch latency hidden under 32 MFMAs) + quiesce
        asm volatile("s_waitcnt vmcnt(0)" ::: "memory");
        __builtin_amdgcn_s_barrier();
    }
#pragma unroll
    for (int mi = 0; mi < 4; ++mi)
#pragma unroll
        for (int ni = 0; ni < 4; ++ni)
#pragma unroll
            for (int r = 0; r < 4; ++r) {
                const int row = bm + wr * 64 + mi * 16 + l4 * 4 + r;
                const int col = bn + wc * 64 + ni * 16 + l15;
                storeC(&C[(size_t)row * N + col], acc[mi][ni][r]);
            }
}

// ---------------------------------------------------------------------------
// permlane32_swap: swaps x[hi lanes] with y[lo lanes].
// VALU-pipe (1.20x vs ds_bpermute, m255). Fallback emulation via shfl.
// ---------------------------------------------------------------------------
#if __has_builtin(__builtin_amdgcn_permlane32_swap)
__device__ __forceinline__ void plswap(unsigned& x, unsigned& y, int) {
    uint2v r = __builtin_amdgcn_permlane32_swap(x, y, false, false);
    x = r[0]; y = r[1];
}
#else
__device__ __forceinline__ void plswap(unsigned& x, unsigned& y, int hi) {
    const unsigned px = __shfl_xor(x, 32, 64);
    const unsigned py = __shfl_xor(y, 32, 64);
    const unsigned nx = hi ? py : x;
    const unsigned ny = hi ? y : px;
    x = nx; y = ny;
}
#endif

__device__ __forceinline__ unsigned cvtpk_bf16(float lo, float hi) {
    unsigned w;
    asm("v_cvt_pk_bf16_f32 %0, %1, %2" : "=v"(w) : "v"(lo), "v"(hi));
    return w;
}
__device__ __forceinline__ float swap_max(float v, int hi) {
    unsigned x = __builtin_bit_cast(unsigned, v), y = x;
    plswap(x, y, hi);
    return fmaxf(__builtin_bit_cast(float, x), __builtin_bit_cast(float, y));
}
__device__ __forceinline__ float swap_add(float v, int hi) {
    unsigned x = __builtin_bit_cast(unsigned, v), y = x;
    plswap(x, y, hi);
    return __builtin_bit_cast(float, x) + __builtin_bit_cast(float, y);
}
// Build PV B-fragment for one 16-kv k-step from 8 own p-values s[R0..R0+7].
template <int R0>
__device__ __forceinline__ bf16x8 build_pfrag(const f32x16& s, int hi) {
    unsigned A0 = cvtpk_bf16(s[R0 + 0], s[R0 + 1]);
    unsigned A1 = cvtpk_bf16(s[R0 + 2], s[R0 + 3]);
    unsigned B0 = cvtpk_bf16(s[R0 + 4], s[R0 + 5]);
    unsigned B1 = cvtpk_bf16(s[R0 + 6], s[R0 + 7]);
    plswap(A0, B0, hi);
    plswap(A1, B1, hi);
    uint4v u; u[0] = A0; u[1] = A1; u[2] = B0; u[3] = B1;
    return __builtin_bit_cast(bf16x8, u);
}

// ---------------------------------------------------------------------------
// Flash attention v11: v10 structure with DEEPER split-KV: slices of 4
// tiles (256 kv) -> 36 slices/head = 1152 blocks (4+/CU, full 32-wave
// residency; VALU-throughput regime). ns(qc)=qc+1; only qc=0 writes direct.
// ---------------------------------------------------------------------------
__global__ __launch_bounds__(512) void attn_kernel(const __hip_bfloat16* __restrict__ QKV,
                                                   const __hip_bfloat16* __restrict__ Vt,
                                                   __hip_bfloat16* __restrict__ O,
                                                   __hip_bfloat16* __restrict__ Opart,
                                                   float* __restrict__ ms,
                                                   int split) {
    const int h = blockIdx.y;
    const int hkv = h >> 2;
    // map blockIdx.x -> (qc, sl); slices of 4 tiles; ns(qc)=qc+1
    int qc = 0, sl = 0, gbase = 0, ns = 1;
    if (!split) {
        qc = 7 - (int)blockIdx.x;
    } else {
        const int x = (int)blockIdx.x;      // 0..35
        int cum = 0;
#pragma unroll
        for (int q = 0; q < 8; ++q) {
            const int n = q + 1;
            if (x >= cum && x < cum + n) { qc = q; sl = x - cum; gbase = cum; }
            cum += n;
        }
        ns = qc + 1;
    }
    const int ntf = 4 * (qc + 1);
    const int t0 = split ? sl * 4 : 0;
    const int t1 = split ? min(t0 + 4, ntf) : ntf;

    const int tid = threadIdx.x;
    const int w = tid >> 6, l = tid & 63;
    const int lq = l & 31, hi = l >> 5;
    const int q0w = qc * 256 + w * 32;
    const int qlane = q0w + lq;

    __shared__ __align__(16) __bf16 Ks[2][64 * 64];  // [kv][d] swizzled
    __shared__ __align__(16) __bf16 Vs[2][64 * 64];  // [d][kv] swizzled

    const __hip_bfloat16* Kg = QKV + D_MODEL + hkv * HEAD_DIM;       // [s][QKV_N]
    const __hip_bfloat16* Vg = Vt + (size_t)hkv * HEAD_DIM * S_LEN;  // [d][S]

    // 512 threads: 1 chunk each per buffer
    auto stage = [&](int buf, int kv0) {
        const int chunk = tid;                    // 0..511
        const int r = chunk >> 3;                 // row 0..63
        const int cs = (chunk & 7) ^ (r & 7);     // pre-swizzled source chunk
        gload_lds16(&Kg[(size_t)(kv0 + r) * QKV_N + cs * 8], &Ks[buf][chunk * 8]);
        gload_lds16(&Vg[(size_t)r * S_LEN + kv0 + cs * 8], &Vs[buf][chunk * 8]);
    };

    // Q as B-operand: lane holds Q[qlane][16f + 8*hi + e]
    bf16x8 qf[4];
#pragma unroll
    for (int f = 0; f < 4; ++f)
        qf[f] = *reinterpret_cast<const bf16x8*>(
            &QKV[(size_t)qlane * QKV_N + h * HEAD_DIM + 16 * f + 8 * hi]);

    f32x16 o0, o1;
#pragma unroll
    for (int r = 0; r < 16; ++r) { o0[r] = 0.f; o1[r] = 0.f; }
    float m_run = -__builtin_inff(), s_run = 0.f;

    stage(0, t0 * 64);

#pragma unroll 1
    for (int t = t0; t < t1; ++t) {
        __syncthreads();                       // tile t staged (vmcnt drained)
        if (t + 1 < t1) stage((t + 1 - t0) & 1, (t + 1) * 64);
        const int kv0 = t * 64;
        if (kv0 <= q0w + 31) {                 // wave-uniform: skip fully-masked
            const __bf16* Kb = Ks[(t - t0) & 1];
            const __bf16* Vb = Vs[(t - t0) & 1];

            // S^T = K · Q^T  (two 32-kv sub-tiles)
            f32x16 s0, s1;
#pragma unroll
            for (int r = 0; r < 16; ++r) { s0[r] = 0.f; s1[r] = 0.f; }
            __builtin_amdgcn_s_setprio(1);
#pragma unroll
            for (int f = 0; f < 4; ++f) {
                const int rr0 = lq;
                const int rr1 = 32 + lq;
                const bf16x8 ka0 = *reinterpret_cast<const bf16x8*>(
                    &Kb[rr0 * 64 + (((2 * f + hi) ^ (rr0 & 7))) * 8]);
                const bf16x8 ka1 = *reinterpret_cast<const bf16x8*>(
                    &Kb[rr1 * 64 + (((2 * f + hi) ^ (rr1 & 7))) * 8]);
                s0 = __builtin_amdgcn_mfma_f32_32x32x16_bf16(ka0, qf[f], s0, 0, 0, 0);
                s1 = __builtin_amdgcn_mfma_f32_32x32x16_bf16(ka1, qf[f], s1, 0, 0, 0);
            }
            __builtin_amdgcn_s_setprio(0);
            // causal mask (only tiles crossing the diagonal)
            if (kv0 + 63 > q0w) {
#pragma unroll
                for (int r = 0; r < 16; ++r) {
                    const int kvb = (r & 3) + 8 * (r >> 2) + 4 * hi;
                    if (kv0 + kvb > qlane) s0[r] = -__builtin_inff();
                    if (kv0 + 32 + kvb > qlane) s1[r] = -__builtin_inff();
                }
            }
            // row max: tree over own 32 regs, then partner exchange
            float ta = fmaxf(s0[0], s1[0]), tb = fmaxf(s0[1], s1[1]);
            float tc = fmaxf(s0[2], s1[2]), td = fmaxf(s0[3], s1[3]);
#pragma unroll
            for (int r = 4; r < 16; r += 4) {
                ta = fmaxf(ta, fmaxf(s0[r], s1[r]));
                tb = fmaxf(tb, fmaxf(s0[r + 1], s1[r + 1]));
                tc = fmaxf(tc, fmaxf(s0[r + 2], s1[r + 2]));
                td = fmaxf(td, fmaxf(s0[r + 3], s1[r + 3]));
            }
            const float m_row = swap_max(fmaxf(fmaxf(ta, tb), fmaxf(tc, td)), hi);

            // defer-max: skip rescale when max grew by <= 8 (exp2 domain)
            if (!__all(m_row <= m_run + 8.0f)) {
                const float mnew = fmaxf(m_run, m_row);
                const float corr = exp2f(m_run - mnew);
                m_run = mnew;
                s_run *= corr;
#pragma unroll
                for (int r = 0; r < 16; ++r) { o0[r] *= corr; o1[r] *= corr; }
            }
            // P = exp2(S - m_run)
#pragma unroll
            for (int r = 0; r < 16; ++r) {
                s0[r] = exp2f(s0[r] - m_run);
                s1[r] = exp2f(s1[r] - m_run);
            }
            // row sum
            float ua = s0[0] + s1[0], ub = s0[1] + s1[1];
            float uc = s0[2] + s1[2], ud = s0[3] + s1[3];
#pragma unroll
            for (int r = 4; r < 16; r += 4) {
                ua += s0[r] + s1[r];
                ub += s0[r + 1] + s1[r + 1];
                uc += s0[r + 2] + s1[r + 2];
                ud += s0[r + 3] + s1[r + 3];
            }
            s_run += swap_add((ua + ub) + (uc + ud), hi);

            // P fragments (k-steps of 16 kv)
            bf16x8 pa[4];
            pa[0] = build_pfrag<0>(s0, hi);
            pa[1] = build_pfrag<8>(s0, hi);
            pa[2] = build_pfrag<0>(s1, hi);
            pa[3] = build_pfrag<8>(s1, hi);

            // O^T += V^T · P^T
            __builtin_amdgcn_s_setprio(1);
#pragma unroll
            for (int ks = 0; ks < 4; ++ks) {
                const int rv0 = lq;
                const int rv1 = 32 + lq;
                const bf16x8 va0 = *reinterpret_cast<const bf16x8*>(
                    &Vb[rv0 * 64 + (((2 * ks + hi) ^ (rv0 & 7))) * 8]);
                const bf16x8 va1 = *reinterpret_cast<const bf16x8*>(
                    &Vb[rv1 * 64 + (((2 * ks + hi) ^ (rv1 & 7))) * 8]);
                o0 = __builtin_amdgcn_mfma_f32_32x32x16_bf16(va0, pa[ks], o0, 0, 0, 0);
                o1 = __builtin_amdgcn_mfma_f32_32x32x16_bf16(va1, pa[ks], o1, 0, 0, 0);
            }
            __builtin_amdgcn_s_setprio(0);
        }
    }

    if (ns == 1) {
        // direct normalized write: O^T[dv][q] -> O[q][h*64+dv]
        const float inv = 1.0f / s_run;
        __hip_bfloat16* orow = O + (size_t)qlane * D_MODEL + h * HEAD_DIM;
#pragma unroll
        for (int rr = 0; rr < 4; ++rr) {
            {
                uint2v u;
                u[0] = cvtpk_bf16(o0[4 * rr] * inv, o0[4 * rr + 1] * inv);
                u[1] = cvtpk_bf16(o0[4 * rr + 2] * inv, o0[4 * rr + 3] * inv);
                *reinterpret_cast<uint2v*>(orow + 8 * rr + 4 * hi) = u;
            }
            {
                uint2v u;
                u[0] = cvtpk_bf16(o1[4 * rr] * inv, o1[4 * rr + 1] * inv);
                u[1] = cvtpk_bf16(o1[4 * rr + 2] * inv, o1[4 * rr + 3] * inv);
                *reinterpret_cast<uint2v*>(orow + 32 + 8 * rr + 4 * hi) = u;
            }
        }
    } else {
        // partial write: unnormalized bf16 O + (m, s) per row
        const int g = h * 36 + gbase + sl;
        const int row = w * 32 + lq;                      // 0..255 within chunk
        __hip_bfloat16* pb = Opart + ((size_t)g * 256 + row) * 64;
#pragma unroll
        for (int rr = 0; rr < 4; ++rr) {
            {
                uint2v u;
                u[0] = cvtpk_bf16(o0[4 * rr], o0[4 * rr + 1]);
                u[1] = cvtpk_bf16(o0[4 * rr + 2], o0[4 * rr + 3]);
                *reinterpret_cast<uint2v*>(pb + 8 * rr + 4 * hi) = u;
            }
            {
                uint2v u;
                u[0] = cvtpk_bf16(o1[4 * rr], o1[4 * rr + 1]);
                u[1] = cvtpk_bf16(o1[4 * rr + 2], o1[4 * rr + 3]);
                *reinterpret_cast<uint2v*>(pb + 32 + 8 * rr + 4 * hi) = u;
            }
        }
        if (hi == 0) {
            const size_t mi = (size_t)g * 256 + row;
            ms[mi * 2] = m_run;
            ms[mi * 2 + 1] = s_run;
        }
    }
}

// ---------------------------------------------------------------------------
// Merge split-KV partials for qc >= 1. grid (7 qc, 8 rowgroup, 32 h), 256 thr.
// ns(qc) = qc+1 (2..8).
// ---------------------------------------------------------------------------
__device__ __constant__ int kCum2[8] = {0, 1, 3, 6, 10, 15, 21, 28};

__global__ __launch_bounds__(256) void attn_merge(const __hip_bfloat16* __restrict__ Opart,
                                                  const float* __restrict__ ms,
                                                  __hip_bfloat16* __restrict__ O) {
    const int qc = 1 + blockIdx.x;                    // 1..7
    const int h = blockIdx.z;
    const int tid = threadIdx.x;
    const int row = blockIdx.y * 32 + (tid >> 3);     // 0..255
    const int dv0 = (tid & 7) * 8;
    const int ns = qc + 1;                            // 2..8
    const int g0 = h * 36 + kCum2[qc];

    float mv[8], sv[8];
    float M = -__builtin_inff();
#pragma unroll
    for (int s = 0; s < 8; ++s) {
        if (s < ns) {
            const size_t mi = (size_t)(g0 + s) * 256 + row;
            mv[s] = ms[mi * 2];
            sv[s] = ms[mi * 2 + 1];
            M = fmaxf(M, mv[s]);
        }
    }
    float S = 0.f;
    float acc[8];
#pragma unroll
    for (int j = 0; j < 8; ++j) acc[j] = 0.f;
#pragma unroll
    for (int s = 0; s < 8; ++s) {
        if (s < ns) {
            const float wgt = exp2f(mv[s] - M);
            S += wgt * sv[s];
            const bf16x8 v = *reinterpret_cast<const bf16x8*>(
                &Opart[((size_t)(g0 + s) * 256 + row) * 64 + dv0]);
#pragma unroll
            for (int j = 0; j < 8; ++j) acc[j] += wgt * (float)v[j];
        }
    }
    const float inv = 1.0f / S;
    uint4v u;
    u[0] = cvtpk_bf16(acc[0] * inv, acc[1] * inv);
    u[1] = cvtpk_bf16(acc[2] * inv, acc[3] * inv);
    u[2] = cvtpk_bf16(acc[4] * inv, acc[5] * inv);
    u[3] = cvtpk_bf16(acc[6] * inv, acc[7] * inv);
    *reinterpret_cast<uint4v*>(&O[(size_t)(qc * 256 + row) * D_MODEL + h * HEAD_DIM + dv0]) = u;
}

// ---------------------------------------------------------------------------
// Launch
// ---------------------------------------------------------------------------
extern "C" void kernel_launch(void* const* d_in, const int* in_sizes, int n_in,
                              void* d_out, int out_size, void* d_ws, size_t ws_size,
                              hipStream_t stream) {
    const float* x  = (const float*)d_in[0];
    const float* wq = (const float*)d_in[1];
    const float* wk = (const float*)d_in[2];
    const float* wv = (const float*)d_in[3];
    const float* wo = (const float*)d_in[4];
    const float* fc = (const float*)d_in[5];
    const float* fs = (const float*)d_in[6];
    float* out = (float*)d_out;

    char* ws = (char*)d_ws;
    __hip_bfloat16* wqkvT = (__hip_bfloat16*)(ws);                 // [3072][2048] bf16, 12 MiB
    __hip_bfloat16* woT   = (__hip_bfloat16*)(ws + (12u << 20));   // [2048][2048], 8 MiB
    __hip_bfloat16* attnb = (__hip_bfloat16*)(ws + (20u << 20));   // [2048][2048], 8 MiB
    __hip_bfloat16* xb    = (__hip_bfloat16*)(ws + (28u << 20));   // [2048][2048], 8 MiB
    __hip_bfloat16* QKV   = (__hip_bfloat16*)(ws + (36u << 20));   // [2048][3072], 12 MiB
    __hip_bfloat16* Vt    = (__hip_bfloat16*)(ws + (48u << 20));   // [512][2048], 2 MiB
    float*          msb   = (float*)(ws + (50u << 20));            // 1152*256*2 f32, 2.4 MiB
    __hip_bfloat16* Opart = (__hip_bfloat16*)(ws + (53u << 20));   // 1152*256*64 bf16, 38 MiB

    const int split = (ws_size >= (96ull << 20)) ? 1 : 0;

    const dim3 tb(32, 8);
    transpose_convert<<<dim3(D_MODEL / 32, D_MODEL / 32), tb, 0, stream>>>(wq, wqkvT, D_MODEL, D_MODEL);
    transpose_convert<<<dim3(KV_DIM / 32, D_MODEL / 32), tb, 0, stream>>>(wk, wqkvT + (size_t)D_MODEL * D_MODEL, D_MODEL, KV_DIM);
    transpose_convert<<<dim3(KV_DIM / 32, D_MODEL / 32), tb, 0, stream>>>(wv, wqkvT + (size_t)(D_MODEL + KV_DIM) * D_MODEL, D_MODEL, KV_DIM);
    transpose_convert<<<dim3(D_MODEL / 32, D_MODEL / 32), tb, 0, stream>>>(wo, woT, D_MODEL, D_MODEL);
    convert_bf16<<<(S_LEN * D_MODEL) / (256 * 8), 256, 0, stream>>>(x, xb);

    // fused QKV projection: [2048][3072]
    gemm_bt<__hip_bfloat16><<<dim3(QKV_N / 128, S_LEN / 128), 256, 0, stream>>>(xb, wqkvT, QKV, S_LEN, QKV_N, D_MODEL);

    // fused RoPE on Q (scaled by 1/8*log2e) and K
    rope_qk<<<(S_LEN * (N_HEADS + N_KV) * 32) / 256, 256, 0, stream>>>(QKV, fc, fs);

    // V transpose to [hkv*64+d][s]
    transpose_v<<<dim3(S_LEN / 64, N_KV), 256, 0, stream>>>(QKV, Vt);

    // causal GQA flash attention (8 waves, 256 q-rows/block, deep split-KV)
    if (split) {
        attn_kernel<<<dim3(36, N_HEADS), 512, 0, stream>>>(QKV, Vt, attnb, Opart, msb, 1);
        attn_merge<<<dim3(7, 8, N_HEADS), 256, 0, stream>>>(Opart, msb, attnb);
    } else {
        attn_kernel<<<dim3(8, N_HEADS), 512, 0, stream>>>(QKV, Vt, attnb, Opart, msb, 0);
    }

    // output projection -> f32
    gemm_bt<float><<<dim3(D_MODEL / 128, S_LEN / 128), 256, 0, stream>>>(attnb, woT, out, S_LEN, D_MODEL, D_MODEL);

    (void)in_sizes; (void)n_in; (void)out_size;
}